// Round 14
// baseline (40.926 us; speedup 1.0000x reference)
//
#include <hip/hip_runtime.h>
#include <math.h>

// SurrogateCanny fused kernel, round 13: packed-FP32 (VOP3P) restructure.
// The two 8-row strips are packed into v2f element pairs (s_sq rows j, j+8):
// all sobel/sq and the decide() fma front run as v_pk_* (2x throughput), the
// strip junction and tz-selects disappear (vertical neighbors are in-register
// packs), and the decide scalar tail + __any exact-fallback stay verbatim
// from R12 (passed absmax 0). 128-thread blocks, 128x16 tile, 1 col/thread.

constexpr int W = 1024, H = 1024;
constexpr int TX = 128, TY = 16;
constexpr int GH = TY + 2, GSTR = 132;   // s_sq rows 0..17, cols p=c+1 (0..129)

typedef float v2f __attribute__((ext_vector_type(2)));

__device__ __forceinline__ v2f splat2(float a) { v2f v; v.x = a; v.y = a; return v; }
__device__ __forceinline__ v2f fma2(float a, v2f b, v2f c) {
  return __builtin_elementwise_fma(splat2(a), b, c);
}

// Packed sobel, bit-identical per element to the verified R12 factored form
// (0.5 products are exact, so the fma folds round at the same points).
__device__ __forceinline__ void sobel_pair2(v2f a00, v2f a01, v2f a02,
                                            v2f a10, v2f a12,
                                            v2f a20, v2f a21, v2f a22,
                                            v2f& gxv, v2f& gyv) {
  v2f t1 = splat2(0.5f) * (a02 - a00);
  v2f t2 = t1 - a10;
  v2f t3 = t2 + a12;
  v2f t4 = fma2(-0.5f, a20, t3);
  gxv = fma2(0.5f, a22, t4);
  v2f p1 = fma2(0.5f, a00, a01);
  v2f p2 = fma2(0.5f, a02, p1);
  v2f u3 = fma2(0.5f, a20, -p2);
  v2f u4 = u3 + a21;
  gyv = fma2(0.5f, a22, u4);
}

// Guarded global load (halo path only).
__device__ __forceinline__ float gld(const float* __restrict__ im, int r, int c) {
  const bool ok = ((unsigned)r < 1024u) && ((unsigned)c < 1024u);
  const int rc = min(max(r, 0), 1023);
  const int cc = min(max(c, 0), 1023);
  const float v = im[rc * W + cc];
  return ok ? v : 0.0f;
}

// Scalar decide tail, verbatim R12 semantics. c1..c4/emin/scl computed packed.
__device__ __forceinline__ float decide_tail(
    float gxv, float gyv, float sc,
    float c1, float c2, float c3, float c4, float emin, float scl,
    float s0a, float s0b, float s1a, float s1b,
    float s2a, float s2b, float s3a, float s3b,
    float thr, float thr2) {
#pragma clang fp contract(off)
  const bool nearb = emin < 0.0f;
  const unsigned sgn = (__float_as_uint(gyv) ^ __float_as_uint(gxv)) >> 31;
  const float m0 = fmaxf(fmaxf(s0a, s0b), thr2);
  const float m1 = fmaxf(fmaxf(s1a, s1b), thr2);
  const float m2 = fmaxf(fmaxf(s2a, s2b), thr2);
  const float m3 = fmaxf(fmaxf(s3a, s3b), thr2);
  float m;
  if (c1 < 0.0f)      m = m0;
  else if (c2 < 0.0f) m = sgn ? m3 : m1;
  else if (c3 < 0.0f) m = m2;
  else if (c4 < 0.0f) m = sgn ? m1 : m3;
  else                m = m0;
  const bool raw  = (sc  > m);
  const bool sure = (scl > m);
  const bool need = nearb || (raw != sure);
  float res = sure ? 1.0f : 0.0f;
  if (__builtin_expect(__any((int)need), 0)) {
    const float C = (float)(360.0 / M_PI);
    float r  = gyv / gxv;
    float t  = atanf(r);
    float u  = t * C;
    float v2 = u + 180.0f;
    float w  = v2 / 45.0f;
    int   kk = (int)rintf(w);
    int   dd = kk & 3;
    float sn1e = (dd == 0) ? s0a : (dd == 1) ? s1a : (dd == 2) ? s2a : s3a;
    float sn2e = (dd == 0) ? s0b : (dd == 1) ? s1b : (dd == 2) ? s2b : s3b;
    float gmc = sqrtf(sc), n1 = sqrtf(sn1e), n2 = sqrtf(sn2e);
    bool keep = (gmc - n1 > 0.0f) && (gmc - n2 > 0.0f) && (gmc - thr > 0.0f);
    float slow = keep ? 1.0f : 0.0f;
    res = need ? slow : res;
  }
  return res;
}

__device__ __forceinline__ v2f decide2(v2f gxv, v2f gyv, v2f sc,
                                       v2f s0a, v2f s0b, v2f s1a, v2f s1b,
                                       v2f s2a, v2f s2b, v2f s3a, v2f s3b,
                                       float thr, float thr2) {
#pragma clang fp contract(off)
  const float T1 = 0.19891236737965801f, D1 = 5.0e-5f;
  const float T2 = 0.66817863791929898f, D2 = 7.0e-5f;
  const float T3 = 1.49660576266548901f, D3 = 1.5e-4f;
  const float T4 = 5.02733949212584810f, D4 = 1.2e-3f;

  const v2f av = __builtin_elementwise_abs(gyv);
  const v2f bv = __builtin_elementwise_abs(gxv);
  const v2f c1 = fma2(-T1, bv, av);
  const v2f c2 = fma2(-T2, bv, av);
  const v2f c3 = fma2(-T3, bv, av);
  const v2f c4 = fma2(-T4, bv, av);
  const v2f e1 = fma2(-D1, bv, __builtin_elementwise_abs(c1));
  const v2f e2 = fma2(-D2, bv, __builtin_elementwise_abs(c2));
  const v2f e3 = fma2(-D3, bv, __builtin_elementwise_abs(c3));
  const v2f e4 = fma2(-D4, bv, __builtin_elementwise_abs(c4));
  const v2f emin = __builtin_elementwise_min(__builtin_elementwise_min(e1, e2),
                                             __builtin_elementwise_min(e3, e4));
  const v2f scl = sc * splat2(0.999998f);

  v2f res;
  res.x = decide_tail(gxv.x, gyv.x, sc.x, c1.x, c2.x, c3.x, c4.x, emin.x, scl.x,
                      s0a.x, s0b.x, s1a.x, s1b.x, s2a.x, s2b.x, s3a.x, s3b.x,
                      thr, thr2);
  res.y = decide_tail(gxv.y, gyv.y, sc.y, c1.y, c2.y, c3.y, c4.y, emin.y, scl.y,
                      s0a.y, s0b.y, s1a.y, s1b.y, s2a.y, s2b.y, s3a.y, s3b.y,
                      thr, thr2);
  return res;
}

__global__ __launch_bounds__(128)
void canny_kernel(const float* __restrict__ img, const float* __restrict__ thrp,
                  float* __restrict__ out) {
#pragma clang fp contract(off)
  __shared__ __align__(16) float s_sq[GH][GSTR];

  const int b   = blockIdx.z;
  const int bx0 = blockIdx.x * TX;
  const int by0 = blockIdx.y * TY;
  const float* im = img + (size_t)b * (W * H);
  float* ob       = out + (size_t)b * (W * H);
  const int tid = threadIdx.x;
  const int c   = tid;                 // owned column (image col bx0+c)
  const bool edge = (bx0 == 0) || (bx0 + TX == W) || (by0 == 0) || (by0 + TY == H);

  const float thr  = *thrp;
  const float thr2 = thr * thr;

  // ---- load 20 img rows x 3 cols; build 12 packs per col (offset-8 pairs) ----
  // Pack element .x = img row by0-2+j, .y = img row by0+6+j (j = 0..11).
  v2f PA0, PA1, PA2, PA3, PA4, PA5, PA6, PA7, PA8, PA9, PA10, PA11;
  v2f PB0, PB1, PB2, PB3, PB4, PB5, PB6, PB7, PB8, PB9, PB10, PB11;
  v2f PC0, PC1, PC2, PC3, PC4, PC5, PC6, PC7, PC8, PC9, PC10, PC11;
  if (!edge) {
    const float* p = im + (size_t)(by0 - 2) * W + (bx0 + c - 1);
#define MKP(J)                                                                 \
    PA##J = (v2f){p[(J) * W + 0], p[((J) + 8) * W + 0]};                       \
    PB##J = (v2f){p[(J) * W + 1], p[((J) + 8) * W + 1]};                       \
    PC##J = (v2f){p[(J) * W + 2], p[((J) + 8) * W + 2]};
    MKP(0) MKP(1) MKP(2) MKP(3) MKP(4) MKP(5)
    MKP(6) MKP(7) MKP(8) MKP(9) MKP(10) MKP(11)
#undef MKP
  } else {
    const int cb = bx0 + c;
    const int ccm1 = max(cb - 1, 0);
    const int ccp1 = min(cb + 1, 1023);
    const bool okL = (cb - 1) >= 0;
    const bool okR = (cb + 1) <= 1023;
    const int r0 = by0 - 2;
    float vA0, vA1, vA2, vA3, vA4, vA5, vA6, vA7, vA8, vA9;
    float vA10, vA11, vA12, vA13, vA14, vA15, vA16, vA17, vA18, vA19;
    float vB0, vB1, vB2, vB3, vB4, vB5, vB6, vB7, vB8, vB9;
    float vB10, vB11, vB12, vB13, vB14, vB15, vB16, vB17, vB18, vB19;
    float vC0, vC1, vC2, vC3, vC4, vC5, vC6, vC7, vC8, vC9;
    float vC10, vC11, vC12, vC13, vC14, vC15, vC16, vC17, vC18, vC19;
#define LOADROW(J)                                                             \
    {                                                                          \
      const int rj = r0 + (J);                                                 \
      const bool rOK = (unsigned)rj < 1024u;      /* wave-uniform */           \
      const int rc = min(max(rj, 0), 1023);                                    \
      const float* rp = im + (size_t)rc * W;                                   \
      const float va = rp[ccm1], vb = rp[cb], vc = rp[ccp1];                   \
      vA##J = (rOK && okL) ? va : 0.0f;                                        \
      vB##J = rOK ? vb : 0.0f;                                                 \
      vC##J = (rOK && okR) ? vc : 0.0f;                                        \
    }
    LOADROW(0) LOADROW(1) LOADROW(2) LOADROW(3) LOADROW(4)
    LOADROW(5) LOADROW(6) LOADROW(7) LOADROW(8) LOADROW(9)
    LOADROW(10) LOADROW(11) LOADROW(12) LOADROW(13) LOADROW(14)
    LOADROW(15) LOADROW(16) LOADROW(17) LOADROW(18) LOADROW(19)
#undef LOADROW
#define MKP(J, J8)                                                             \
    PA##J = (v2f){vA##J, vA##J8};                                              \
    PB##J = (v2f){vB##J, vB##J8};                                              \
    PC##J = (v2f){vC##J, vC##J8};
    MKP(0, 8) MKP(1, 9) MKP(2, 10) MKP(3, 11) MKP(4, 12) MKP(5, 13)
    MKP(6, 14) MKP(7, 15) MKP(8, 16) MKP(9, 17) MKP(10, 18) MKP(11, 19)
#undef MKP
  }

  // ---- GM phase: 10 packed row-pairs -> s_sq rows (j, j+8), j = 0..9 ----
  // (rows 8,9 computed twice with identical inputs -> identical bits, benign)
  v2f sq0, sq1, sq2v, sq3, sq4, sq5, sq6, sq7, sq8, sq9;
  v2f ga0, ga1, ga2, ga3, ga4, ga5, ga6, ga7, ga8, ga9;
  v2f gb0, gb1, gb2, gb3, gb4, gb5, gb6, gb7, gb8, gb9;
#define GM_PAIR(J, A0, B0, C0, A1, C1, A2, B2, C2, SQ, GX, GY)                 \
  {                                                                            \
    sobel_pair2(A0, B0, C0, A1, C1, A2, B2, C2, GX, GY);                       \
    SQ = GX * GX + GY * GY;                                                    \
    if (edge) {                                                                \
      if ((unsigned)(by0 + (J) - 1) >= 1024u) SQ.x = 0.0f;                     \
      if ((unsigned)(by0 + (J) + 7) >= 1024u) SQ.y = 0.0f;                     \
    }                                                                          \
    s_sq[(J)][c + 1] = SQ.x;                                                   \
    s_sq[(J) + 8][c + 1] = SQ.y;                                               \
  }
  GM_PAIR(0, PA0, PB0, PC0, PA1, PC1, PA2, PB2, PC2, sq0, ga0, gb0)
  GM_PAIR(1, PA1, PB1, PC1, PA2, PC2, PA3, PB3, PC3, sq1, ga1, gb1)
  GM_PAIR(2, PA2, PB2, PC2, PA3, PC3, PA4, PB4, PC4, sq2v, ga2, gb2)
  GM_PAIR(3, PA3, PB3, PC3, PA4, PC4, PA5, PB5, PC5, sq3, ga3, gb3)
  GM_PAIR(4, PA4, PB4, PC4, PA5, PC5, PA6, PB6, PC6, sq4, ga4, gb4)
  GM_PAIR(5, PA5, PB5, PC5, PA6, PC6, PA7, PB7, PC7, sq5, ga5, gb5)
  GM_PAIR(6, PA6, PB6, PC6, PA7, PC7, PA8, PB8, PC8, sq6, ga6, gb6)
  GM_PAIR(7, PA7, PB7, PC7, PA8, PC8, PA9, PB9, PC9, sq7, ga7, gb7)
  GM_PAIR(8, PA8, PB8, PC8, PA9, PC9, PA10, PB10, PC10, sq8, ga8, gb8)
  GM_PAIR(9, PA9, PB9, PC9, PA10, PC10, PA11, PB11, PC11, sq9, ga9, gb9)
#undef GM_PAIR

  // halo cols c=-1 (p=0) and c=128 (p=129): s_sq rows 0..17 -> 36 elements
  if (tid < 36) {
    int rr = tid >> 1;                     // 0..17, gm row r = rr-1
    int r  = rr - 1;
    int cc = (tid & 1) ? 128 : -1;
    int hr = by0 - 2 + rr;
    int hc = bx0 + cc;
    float gxv, gyv;
    {
      float a00 = gld(im, hr, hc - 1),     a01 = gld(im, hr, hc),     a02 = gld(im, hr, hc + 1);
      float a10 = gld(im, hr + 1, hc - 1),                            a12 = gld(im, hr + 1, hc + 1);
      float a20 = gld(im, hr + 2, hc - 1), a21 = gld(im, hr + 2, hc), a22 = gld(im, hr + 2, hc + 1);
      float t1 = 0.5f * (a02 - a00);
      float t2 = t1 - a10;
      float t3 = t2 + a12;
      float t4 = fmaf(-0.5f, a20, t3);
      gxv = fmaf(0.5f, a22, t4);
      float p1 = fmaf(0.5f, a00, a01);
      float p2 = fmaf(0.5f, a02, p1);
      float u3 = fmaf(0.5f, a20, -p2);
      float u4 = u3 + a21;
      gyv = fmaf(0.5f, a22, u4);
    }
    float sq = gxv * gxv + gyv * gyv;
    if (!((unsigned)(by0 + r) < 1024u && (unsigned)(bx0 + cc) < 1024u)) sq = 0.0f;
    s_sq[rr][cc + 1] = sq;
  }
  __syncthreads();

  // ---- pixel phase: 8 packed pixel-pairs (rows by0+k and by0+k+8) ----
  {
    // L/R neighbor-column packs: element .x = s_sq[j], .y = s_sq[j+8]
    v2f L0 = (v2f){s_sq[0][c], s_sq[8][c]},   R0 = (v2f){s_sq[0][c + 2], s_sq[8][c + 2]};
    v2f L1 = (v2f){s_sq[1][c], s_sq[9][c]},   R1 = (v2f){s_sq[1][c + 2], s_sq[9][c + 2]};
    v2f L2 = (v2f){s_sq[2][c], s_sq[10][c]},  R2 = (v2f){s_sq[2][c + 2], s_sq[10][c + 2]};
    v2f L3 = (v2f){s_sq[3][c], s_sq[11][c]},  R3 = (v2f){s_sq[3][c + 2], s_sq[11][c + 2]};
    v2f L4 = (v2f){s_sq[4][c], s_sq[12][c]},  R4 = (v2f){s_sq[4][c + 2], s_sq[12][c + 2]};
    v2f L5 = (v2f){s_sq[5][c], s_sq[13][c]},  R5 = (v2f){s_sq[5][c + 2], s_sq[13][c + 2]};
    v2f L6 = (v2f){s_sq[6][c], s_sq[14][c]},  R6 = (v2f){s_sq[6][c + 2], s_sq[14][c + 2]};
    v2f L7 = (v2f){s_sq[7][c], s_sq[15][c]},  R7 = (v2f){s_sq[7][c + 2], s_sq[15][c + 2]};
    v2f L8 = (v2f){s_sq[8][c], s_sq[16][c]},  R8 = (v2f){s_sq[8][c + 2], s_sq[16][c + 2]};
    v2f L9 = (v2f){s_sq[9][c], s_sq[17][c]},  R9 = (v2f){s_sq[9][c + 2], s_sq[17][c + 2]};

    float* o = ob + (size_t)by0 * W + bx0 + c;

    // pair k: sc=sq[k+1]; d0:(R[k+1],L[k+1]) d1:(R[k],L[k+2])
    //         d2:(sq[k],sq[k+2]) d3:(L[k],R[k+2])
#define PIX(K, SCM, SC, SCP, LKM, LK, LKP, RKM, RK, RKP, GX, GY)               \
    {                                                                          \
      v2f r = decide2(GX, GY, SC, RK, LK, RKM, LKP, SCM, SCP, LKM, RKP,        \
                      thr, thr2);                                              \
      o[(K) * W] = r.x;                                                        \
      o[((K) + 8) * W] = r.y;                                                  \
    }
    PIX(0, sq0, sq1, sq2v, L0, L1, L2, R0, R1, R2, ga1, gb1)
    PIX(1, sq1, sq2v, sq3, L1, L2, L3, R1, R2, R3, ga2, gb2)
    PIX(2, sq2v, sq3, sq4, L2, L3, L4, R2, R3, R4, ga3, gb3)
    PIX(3, sq3, sq4, sq5, L3, L4, L5, R3, R4, R5, ga4, gb4)
    PIX(4, sq4, sq5, sq6, L4, L5, L6, R4, R5, R6, ga5, gb5)
    PIX(5, sq5, sq6, sq7, L5, L6, L7, R5, R6, R7, ga6, gb6)
    PIX(6, sq6, sq7, sq8, L6, L7, L8, R6, R7, R8, ga7, gb7)
    PIX(7, sq7, sq8, sq9, L7, L8, L9, R7, R8, R9, ga8, gb8)
#undef PIX
  }
}

extern "C" void kernel_launch(void* const* d_in, const int* in_sizes, int n_in,
                              void* d_out, int out_size, void* d_ws, size_t ws_size,
                              hipStream_t stream) {
  const float* img = (const float*)d_in[0];
  const float* thr = (const float*)d_in[4];
  float* out = (float*)d_out;
  const int batch = in_sizes[0] / (W * H);

  dim3 grid(W / TX, H / TY, batch);
  canny_kernel<<<grid, dim3(128), 0, stream>>>(img, thr, out);
}